// Round 5
// baseline (158.557 us; speedup 1.0000x reference)
//
#include <hip/hip_runtime.h>
#include <hip/hip_bf16.h>
#include <stdint.h>

#define SDEP 128
#define NRES 256
#define CZQ 128

typedef __bf16 v8bf __attribute__((ext_vector_type(8)));
typedef __bf16 v4bf __attribute__((ext_vector_type(4)));
typedef float v16f __attribute__((ext_vector_type(16)));

// full-wave sum via DPP (VALU pipe, no LDS). Result valid in lane 63.
__device__ __forceinline__ float dpp_wave_sum(float x) {
  float t;
#define STEP(ctrl)                                                         \
  t = __builtin_bit_cast(float, __builtin_amdgcn_update_dpp(               \
          0, __builtin_bit_cast(int, x), ctrl, 0xF, 0xF, true));           \
  x += t;
  STEP(0x111)
  STEP(0x112)
  STEP(0x114)
  STEP(0x118)
  STEP(0x142)
  STEP(0x143)
#undef STEP
  return x;
}
__device__ __forceinline__ float lane63(float x) {
  return __builtin_bit_cast(float,
      __builtin_amdgcn_readlane(__builtin_bit_cast(int, x), 63));
}

#define MFMA32(a, b, c) __builtin_amdgcn_mfma_f32_32x32x16_bf16(a, b, c, 0, 0, 0)

// ---------------- Kernel A: fused prep + LN + projections ------------
// 256 blocks x 512 thr, 1 block/CU, 1 round. (unchanged, proven)
__global__ __launch_bounds__(512, 2) void fusedA_kernel(
    const float* __restrict__ msa, const float* __restrict__ lnw,
    const float* __restrict__ lnb, const float* __restrict__ wl,
    const float* __restrict__ wr, const float* __restrict__ mask,
    const float* __restrict__ wo, const float* __restrict__ bl,
    const float* __restrict__ br,
    __bf16* __restrict__ At2, __bf16* __restrict__ Bt2,
    float* __restrict__ rnorm, __bf16* __restrict__ wot4)
{
  __shared__ __bf16 xs[128 * 258];      // 66 KB
  __shared__ __bf16 wcs[16384];         // 32 KB
  __shared__ __bf16 Ls[8 * 32 * 36];    // 18 KB

  const int i = blockIdx.x, t = threadIdx.x;
  const int w = t >> 6, lane = t & 63;
  const int half = lane >> 5, l31 = lane & 31;
  const int sb = w >> 1, nh = w & 1;

  #pragma unroll
  for (int u = 0; u < 32; ++u) {
    int idx = u * 512 + t;
    int j = idx & 7, n = (idx >> 3) & 31, hf = (idx >> 8) & 1;
    int ks = (idx >> 9) & 15, tile = idx >> 13;
    const float* wsrc = tile ? wr : wl;
    wcs[idx] = (__bf16)wsrc[(ks * 16 + hf * 8 + j) * 32 + n];
  }

  const float4 wv4 = ((const float4*)lnw)[lane];
  const float4 bv4 = ((const float4*)lnb)[lane];

  #pragma unroll 8
  for (int r = 0; r < 16; ++r) {
    const int s = sb * 32 + nh * 16 + r;
    float4 x = ((const float4*)(msa + ((size_t)s * 256 + i) * 256))[lane];
    float s1 = dpp_wave_sum(x.x + x.y + x.z + x.w);
    float s2 = dpp_wave_sum(x.x * x.x + x.y * x.y + x.z * x.z + x.w * x.w);
    float mu = lane63(s1) * (1.f / 256.f);
    float var = lane63(s2) * (1.f / 256.f) - mu * mu;
    float rs = rsqrtf(var + 1e-5f);
    v4bf o;
    o[0] = (__bf16)((x.x - mu) * rs * wv4.x + bv4.x);
    o[1] = (__bf16)((x.y - mu) * rs * wv4.y + bv4.y);
    o[2] = (__bf16)((x.z - mu) * rs * wv4.z + bv4.z);
    o[3] = (__bf16)((x.w - mu) * rs * wv4.w + bv4.w);
    *(v4bf*)(xs + s * 258 + lane * 4) = o;
  }
  __syncthreads();

  v16f acc;
  #pragma unroll
  for (int r = 0; r < 16; ++r) acc[r] = 0.f;

  const __bf16* xrow = xs + (sb * 32 + l31) * 258 + half * 8;
  const __bf16* bbase = wcs + nh * 8192 + half * 256 + l31 * 8;
  #pragma unroll
  for (int ks = 0; ks < 16; ++ks) {
    v8bf a = *(const v8bf*)(xrow + ks * 16);
    v8bf b = *(const v8bf*)(bbase + ks * 512);
    acc = MFMA32(a, b, acc);
  }

  __bf16* Lw = Ls + w * 32 * 36;
  const float bias = (nh ? br : bl)[l31];
  #pragma unroll
  for (int r = 0; r < 16; ++r) {
    int sl = (r & 3) + 8 * (r >> 2) + 4 * half;
    float mv = mask[(sb * 32 + sl) * NRES + i];
    Lw[l31 * 36 + sl] = (__bf16)((acc[r] + bias) * mv);
  }

  __bf16* dst = nh ? Bt2 : At2;
  const int c = lane >> 1, jq = (lane & 1) * 4;
  #pragma unroll
  for (int o = 0; o < 4; ++o) {
    v4bf v = *(const v4bf*)(Lw + c * 36 + o * 8 + jq);
    *(v4bf*)(dst + ((size_t)i * 16 + sb * 4 + o) * 256 + lane * 4) = v;
  }

  if (i < 128) {
    const int b = i * 2 + (t >> 8), col = t & 255;
    float a0 = 0.f;
    #pragma unroll 4
    for (int s = 0; s < SDEP; ++s)
      a0 += mask[s * NRES + b] * mask[s * NRES + col];
    rnorm[b * NRES + col] = 1.f / fmaxf(a0, 1.f);
  } else {
    #pragma unroll
    for (int u = 0; u < 2; ++u) {
      int idx = (i - 128) * 1024 + u * 512 + t;
      int j = idx & 7, lc = (idx >> 3) & 63, kk = (idx >> 9) & 63, zg = idx >> 15;
      int k = kk * 16 + (lc >> 5) * 8 + j;
      int z = zg * 32 + (lc & 31);
      wot4[idx] = (__bf16)wo[k * CZQ + z];
    }
  }
}

// ---------------- Kernel B: pipelined dual-tile outer + out proj -----
// R11 = R10 with P3 ring-order fix: loop body reads bb BEFORE issuing the
// ws ring load (P2's proven order). R10 hoisted the load to the top of the
// body, so at kk=16..23 ws[(kk-16)&7] was overwritten with elem kk+8
// before being read -> tile-B used wrong wot rows for 8/32 K-steps.
//  P1: G1(A) -> Ps[0]                              (barrier)
//  P2: G2(A) kk-loop interleaved with G1(B) loads+MFMAs -> redb[0], Ps[1]
//                                                   (barrier)
//  P3: G2(B) kk-loop interleaved with reduce+store(A) -> redb[1]
//                                                   (barrier) store(B)
__global__ __launch_bounds__(512, 2) void outer_kernel(
    const __bf16* __restrict__ At2, const __bf16* __restrict__ Bt2,
    const float* __restrict__ rnorm, const __bf16* __restrict__ wot4,
    const float* __restrict__ bo, float* __restrict__ out)
{
  __shared__ __bf16 Ps[2][32 * 1032];   // 132096 B  [tile][p][c*32+d]
  __shared__ __bf16 redb[2][4 * 1024];  // 16384 B   [tile][zg][cc*32+l31]

  const int tid = threadIdx.x;
  const int w = tid >> 6, lane = tid & 63;
  const int half = lane >> 5, l31 = lane & 31;
  const int bxp = blockIdx.x;           // 0..15 -> j units bxp*16 .. +15
  const int by = blockIdx.y;            // 0..63 -> i units by*4 .. +3
  const int mh = w >> 2;                // i-pair (0..1)     [GEMM1 role]
  const int nq = w & 3;                 // j-pair (0..3)
  const int zg = w & 3;                 // z-quarter (0..3)  [GEMM2 role]
  const int kh = w >> 2;                // K-half (0..1)

  const __bf16* Ap  = At2 + ((size_t)(by * 4 + mh * 2)) * 4096 + l31 * 8;
  const __bf16* BpA = Bt2 + ((size_t)(bxp * 16 + nq * 2)) * 4096 + l31 * 8;
  const __bf16* BpB = BpA + 8 * 4096;
  const __bf16* wp =
      wot4 + ((size_t)((zg * 64 + kh * 32) * 64) + half * 32 + l31) * 8;
  const float bz = bo[zg * 32 + l31];

  // rnorm for tile A
  float rnA[2][2];
  #pragma unroll
  for (int ti = 0; ti < 2; ++ti)
    #pragma unroll
    for (int tj = 0; tj < 2; ++tj)
      rnA[ti][tj] =
          rnorm[(by * 4 + mh * 2 + ti) * NRES + bxp * 16 + nq * 2 + tj];

  v8bf wb[16];  // wot resident: elements 0..15 of this wave's slice

  // ================= P1: G1(tileA) =================
  {
    v16f aca[2][2];
    #pragma unroll
    for (int a = 0; a < 2; ++a)
      #pragma unroll
      for (int b = 0; b < 2; ++b)
        #pragma unroll
        for (int r = 0; r < 16; ++r) aca[a][b][r] = 0.f;

    #pragma unroll
    for (int ks = 0; ks < 8; ++ks) {
      const int off = (ks * 2 + half) * 256;
      v8bf a0 = *(const v8bf*)(Ap + off);
      v8bf a1 = *(const v8bf*)(Ap + 4096 + off);
      v8bf b0 = *(const v8bf*)(BpA + off);
      v8bf b1 = *(const v8bf*)(BpA + 4096 + off);
      aca[0][0] = MFMA32(a0, b0, aca[0][0]);
      aca[0][1] = MFMA32(a0, b1, aca[0][1]);
      aca[1][0] = MFMA32(a1, b0, aca[1][0]);
      aca[1][1] = MFMA32(a1, b1, aca[1][1]);
    }

    // wot prefetch (issue before Ps write; latency hides under barrier)
    #pragma unroll
    for (int u = 0; u < 16; ++u) wb[u] = *(const v8bf*)(wp + u * 512);

    #pragma unroll
    for (int ti = 0; ti < 2; ++ti) {
      #pragma unroll
      for (int tj = 0; tj < 2; ++tj) {
        const int p = (mh * 2 + ti) * 8 + nq * 2 + tj;
        #pragma unroll
        for (int r = 0; r < 16; ++r) {
          int cc = (r & 3) + 8 * (r >> 2) + 4 * half;
          Ps[0][p * 1032 + cc * 32 + l31] = (__bf16)(aca[ti][tj][r] * rnA[ti][tj]);
        }
      }
    }
  }

  // rnorm for tile B (prefetch; hides under barrier)
  float rnB[2][2];
  #pragma unroll
  for (int ti = 0; ti < 2; ++ti)
    #pragma unroll
    for (int tj = 0; tj < 2; ++tj)
      rnB[ti][tj] =
          rnorm[(by * 4 + mh * 2 + ti) * NRES + bxp * 16 + 8 + nq * 2 + tj];

  __syncthreads();  // barrier 1: Ps[0] ready

  // ================= P2: G2(A) fused with G1(B) =================
  const __bf16* ppA = &Ps[0][l31 * 1032 + kh * 512 + half * 8];
  const __bf16* ppB = &Ps[1][l31 * 1032 + kh * 512 + half * 8];

  v16f c2a0, c2a1, acb[2][2];
  #pragma unroll
  for (int r = 0; r < 16; ++r) { c2a0[r] = 0.f; c2a1[r] = 0.f; }
  #pragma unroll
  for (int a = 0; a < 2; ++a)
    #pragma unroll
    for (int b = 0; b < 2; ++b)
      #pragma unroll
      for (int r = 0; r < 16; ++r) acb[a][b][r] = 0.f;

  {
    v8bf la[2][4];   // G1(B) chunk double-buffer (compile-time indexed)
    v8bf ws[8];      // wot stream ring (elements 16..31)

    // pre-issue G1(B) chunk 0 (consumed at kk=2)
    {
      const int off = half * 256;
      la[0][0] = *(const v8bf*)(Ap + off);
      la[0][1] = *(const v8bf*)(Ap + 4096 + off);
      la[0][2] = *(const v8bf*)(BpB + off);
      la[0][3] = *(const v8bf*)(BpB + 4096 + off);
    }

    #pragma unroll
    for (int kk = 0; kk < 32; ++kk) {
      v8bf aa = *(const v8bf*)(ppA + kk * 16);
      v8bf bb = (kk < 16) ? wb[kk] : ws[(kk - 16) & 7];
      if (kk & 1) c2a1 = MFMA32(aa, bb, c2a1);
      else        c2a0 = MFMA32(aa, bb, c2a0);

      // wot stream: load element kk+8 (8-step distance), elems 16..31
      // (AFTER the bb read -- read-then-write ring order)
      if (kk >= 8 && kk < 24)
        ws[(kk - 8) & 7] = *(const v8bf*)(wp + (kk + 8) * 512);

      // issue next G1(B) chunk (6-step load-to-use distance)
      if ((kk & 3) == 0 && kk < 28) {
        const int g = (kk >> 2) + 1;
        const int off = (g * 2 + half) * 256;
        la[g & 1][0] = *(const v8bf*)(Ap + off);
        la[g & 1][1] = *(const v8bf*)(Ap + 4096 + off);
        la[g & 1][2] = *(const v8bf*)(BpB + off);
        la[g & 1][3] = *(const v8bf*)(BpB + 4096 + off);
      }
      // consume G1(B) chunk
      if ((kk & 3) == 2) {
        const int g = kk >> 2;
        v8bf a0 = la[g & 1][0], a1 = la[g & 1][1];
        v8bf b0 = la[g & 1][2], b1 = la[g & 1][3];
        acb[0][0] = MFMA32(a0, b0, acb[0][0]);
        acb[0][1] = MFMA32(a0, b1, acb[0][1]);
        acb[1][0] = MFMA32(a1, b0, acb[1][0]);
        acb[1][1] = MFMA32(a1, b1, acb[1][1]);
      }
    }
  }

  // c2a = c2a0 + c2a1 ; K-split partials (kh==1) -> redb[0]
  v16f c2a;
  #pragma unroll
  for (int r = 0; r < 16; ++r) c2a[r] = c2a0[r] + c2a1[r];
  if (kh == 1) {
    #pragma unroll
    for (int r = 0; r < 16; ++r) {
      int cc = (r & 3) + 8 * (r >> 2) + 4 * half;
      redb[0][zg * 1024 + cc * 32 + l31] = (__bf16)c2a[r];
    }
  }

  // Ps[1] write (tile B P-matrix)
  #pragma unroll
  for (int ti = 0; ti < 2; ++ti) {
    #pragma unroll
    for (int tj = 0; tj < 2; ++tj) {
      const int p = (mh * 2 + ti) * 8 + nq * 2 + tj;
      #pragma unroll
      for (int r = 0; r < 16; ++r) {
        int cc = (r & 3) + 8 * (r >> 2) + 4 * half;
        Ps[1][p * 1032 + cc * 32 + l31] = (__bf16)(acb[ti][tj][r] * rnB[ti][tj]);
      }
    }
  }

  // re-prefetch wot elements 0..15 for tile B (L2-hot now)
  #pragma unroll
  for (int u = 0; u < 16; ++u) wb[u] = *(const v8bf*)(wp + u * 512);

  __syncthreads();  // barrier 2: Ps[1] + redb[0] ready

  // ================= P3: G2(B) fused with reduce+store(A) =============
  v16f c2b0, c2b1;
  #pragma unroll
  for (int r = 0; r < 16; ++r) { c2b0[r] = 0.f; c2b1[r] = 0.f; }

  {
    v8bf ws[8];
    // kk 0..7 first (get the MFMA chain going); issue ring loads too
    #pragma unroll
    for (int kk = 0; kk < 8; ++kk) {
      v8bf aa = *(const v8bf*)(ppB + kk * 16);
      v8bf bb = wb[kk];
      if (kk & 1) c2b1 = MFMA32(aa, bb, c2b1);
      else        c2b0 = MFMA32(aa, bb, c2b0);
    }

    // reduce+store(A): independent of c2b chain, drains under MFMAs
    if (kh == 0) {
      #pragma unroll
      for (int r = 0; r < 16; ++r) {
        int cc = (r & 3) + 8 * (r >> 2) + 4 * half;
        int i = by * 4 + (cc >> 3);
        float va = c2a[r] + (float)redb[0][zg * 1024 + cc * 32 + l31] + bz;
        out[((size_t)i * NRES + bxp * 16 + (cc & 7)) * CZQ + zg * 32 + l31] = va;
      }
    }

    #pragma unroll
    for (int kk = 8; kk < 32; ++kk) {
      // read bb FIRST (ring read-then-write order; R10's bug was here)
      v8bf aa = *(const v8bf*)(ppB + kk * 16);
      v8bf bb = (kk < 16) ? wb[kk] : ws[(kk - 16) & 7];
      if (kk & 1) c2b1 = MFMA32(aa, bb, c2b1);
      else        c2b0 = MFMA32(aa, bb, c2b0);

      // wot stream (8-step distance; elements 16..31 loaded at kk 8..23)
      if (kk < 24)
        ws[(kk - 8) & 7] = *(const v8bf*)(wp + (kk + 8) * 512);
    }
  }

  v16f c2b;
  #pragma unroll
  for (int r = 0; r < 16; ++r) c2b[r] = c2b0[r] + c2b1[r];

  if (kh == 1) {
    #pragma unroll
    for (int r = 0; r < 16; ++r) {
      int cc = (r & 3) + 8 * (r >> 2) + 4 * half;
      redb[1][zg * 1024 + cc * 32 + l31] = (__bf16)c2b[r];
    }
  }
  __syncthreads();  // barrier 3: redb[1] ready

  if (kh == 0) {
    #pragma unroll
    for (int r = 0; r < 16; ++r) {
      int cc = (r & 3) + 8 * (r >> 2) + 4 * half;
      int i = by * 4 + (cc >> 3);
      float vb = c2b[r] + (float)redb[1][zg * 1024 + cc * 32 + l31] + bz;
      out[((size_t)i * NRES + bxp * 16 + 8 + (cc & 7)) * CZQ + zg * 32 + l31] = vb;
    }
  }
}

extern "C" void kernel_launch(void* const* d_in, const int* in_sizes, int n_in,
                              void* d_out, int out_size, void* d_ws, size_t ws_size,
                              hipStream_t stream) {
  const float* msa  = (const float*)d_in[0];
  const float* mask = (const float*)d_in[1];
  const float* lnw  = (const float*)d_in[2];
  const float* lnb  = (const float*)d_in[3];
  const float* wl   = (const float*)d_in[4];
  const float* bl   = (const float*)d_in[5];
  const float* wr   = (const float*)d_in[6];
  const float* br   = (const float*)d_in[7];
  const float* wo   = (const float*)d_in[8];
  const float* bo   = (const float*)d_in[9];
  float* out = (float*)d_out;

  char* ws = (char*)d_ws;
  __bf16* At2   = (__bf16*)(ws);                    // 2 MB
  __bf16* Bt2   = (__bf16*)(ws + 2097152);          // 2 MB
  float*  rnorm = (float*)(ws + 4194304);           // 256 KB
  __bf16* wot4  = (__bf16*)(ws + 4456448);          // 256 KB

  fusedA_kernel<<<256, 512, 0, stream>>>(msa, lnw, lnb, wl, wr, mask, wo,
                                         bl, br, At2, Bt2, rnorm, wot4);
  outer_kernel<<<dim3(16, 64), 512, 0, stream>>>(At2, Bt2, rnorm, wot4, bo, out);
}